// Round 13
// baseline (1382.042 us; speedup 1.0000x reference)
//
#include <hip/hip_runtime.h>

#define NN 50000
#define NE 1600000

using bf16x8 = __bf16 __attribute__((ext_vector_type(8)));
using bf16x4 = __bf16 __attribute__((ext_vector_type(4)));
using bf16x2 = __bf16 __attribute__((ext_vector_type(2)));
using f32x4  = float  __attribute__((ext_vector_type(4)));

__device__ __forceinline__ char* swzp(void* base, int row, int byteoff) {
  return (char*)base + (byteoff ^ ((row & 7) << 4));
}
__device__ __forceinline__ const char* swzpc(const void* base, int row, int byteoff) {
  return (const char*)base + (byteoff ^ ((row & 7) << 4));
}

// edge_index may be int32 (JAX default, x64 disabled) or int64. Runtime-detected flag.
__device__ __forceinline__ int ld_idx(const void* p, int f64, long long i) {
  return f64 ? (int)((const long long*)p)[i] : ((const int*)p)[i];
}

__global__ void detect_idx64(const int* ei32, int* flag) {
  __shared__ int anynz;
  if (threadIdx.x == 0) anynz = 0;
  __syncthreads();
  if (ei32[2 * threadIdx.x + 1] != 0) atomicOr(&anynz, 1);
  __syncthreads();
  if (threadIdx.x == 0) *flag = (anynz == 0) ? 1 : 0;
}

__global__ void prep_weights(const float* We, const float* Whu, const float* Whw,
                             const float* W2, const float* Wemb, const float* Wattr,
                             __bf16* wHUW, __bf16* wET2, __bf16* wE, __bf16* wA) {
  int i = blockIdx.x * 256 + threadIdx.x;
  if (i < 65536) {
    int n = i >> 8, k = i & 255;
    wHUW[i] = (__bf16)(n < 128 ? Whu[n * 256 + k] : Whw[(n - 128) * 256 + k]);
  } else if (i < 131072) {
    int j = i - 65536; int n = j >> 8, k = j & 255;
    wET2[j] = (__bf16)(n < 128 ? Wemb[n * 256 + k] : W2[(n - 128) * 256 + k]);
  } else if (i < 147456) {
    int j = i - 131072; wE[j] = (__bf16)We[j];
  } else {
    int j = i - 147456; wA[j] = (__bf16)Wattr[j];
  }
}

// ---- counting sort of edges by tgt ----
__global__ void k_hist(const void* ei, const int* flag, int* cnt) {
  int i = blockIdx.x * 256 + threadIdx.x;
  int t = ld_idx(ei, *flag, (long long)NE + i);
  atomicAdd(&cnt[t], 1);
}

__global__ void k_part(const int* cnt, int* part) {
  __shared__ int red[256];
  int i = blockIdx.x * 256 + threadIdx.x;
  red[threadIdx.x] = (i < NN) ? cnt[i] : 0;
  __syncthreads();
  for (int s = 128; s > 0; s >>= 1) {
    if (threadIdx.x < s) red[threadIdx.x] += red[threadIdx.x + s];
    __syncthreads();
  }
  if (threadIdx.x == 0) part[blockIdx.x] = red[0];
}

__global__ void k_scanpart(int* part, int n) {
  __shared__ int sc[256];
  int v = (threadIdx.x < n) ? part[threadIdx.x] : 0;
  sc[threadIdx.x] = v;
  __syncthreads();
  for (int d = 1; d < 256; d <<= 1) {
    int add = (threadIdx.x >= d) ? sc[threadIdx.x - d] : 0;
    __syncthreads();
    sc[threadIdx.x] += add;
    __syncthreads();
  }
  if (threadIdx.x < n) part[threadIdx.x] = sc[threadIdx.x] - v;  // exclusive
}

__global__ void k_offsets(const int* cnt, const int* part, int* offs) {
  __shared__ int sc[256];
  int i = blockIdx.x * 256 + threadIdx.x;
  int v = (i < NN) ? cnt[i] : 0;
  sc[threadIdx.x] = v;
  __syncthreads();
  for (int d = 1; d < 256; d <<= 1) {
    int add = (threadIdx.x >= d) ? sc[threadIdx.x - d] : 0;
    __syncthreads();
    sc[threadIdx.x] += add;
    __syncthreads();
  }
  if (i < NN) offs[i] = part[blockIdx.x] + sc[threadIdx.x] - v;  // exclusive
}

__global__ void k_scatter(const void* ei, const int* flag, const int* offs,
                          int* fill, int* perm) {
  int i = blockIdx.x * 256 + threadIdx.x;
  int t = ld_idx(ei, *flag, (long long)NE + i);
  int pos = offs[t] + atomicAdd(&fill[t], 1);
  perm[pos] = i;
}

// Swapped-orientation node GEMM, K-split staging: sW holds one 64 KB K-half
// (256 out x 128 k), two passes with persistent accumulators -> 2 blocks/CU.
// MODE 0: hu/hw bf16 outputs (W = [W_hu; W_hw]).
// MODE 1: out = emb + lrelu(t2 + sums/max(cnt,1))  (W = [W_emb; W2]).
template <int MODE>
__global__ __launch_bounds__(512, 4) void node_gemm(
    const float* __restrict__ x, const __bf16* __restrict__ W,
    __bf16* __restrict__ hu, __bf16* __restrict__ hw,
    const float* __restrict__ sums, const int* __restrict__ cnt,
    float* __restrict__ out) {
  __shared__ __bf16 sW[256 * 128];  // 64 KB, one K-half, XOR-swizzled
  const int t = threadIdx.x;
  const int lane = t & 63;
  const int w = t >> 6;      // 0..7
  const int h = lane >> 4;   // 0..3
  const int l15 = lane & 15;

  const int ntiles = (NN + 127) / 128;  // 391
  for (int tile = blockIdx.x; tile < ntiles; tile += gridDim.x) {
    int m0 = tile * 128 + w * 16;
    const bool active = (m0 < NN);     // NN % 16 == 0: waves never partial
    int node = m0 + l15;

    f32x4 acc[16];
#pragma unroll
    for (int n = 0; n < 16; ++n) { acc[n][0] = 0.f; acc[n][1] = 0.f; acc[n][2] = 0.f; acc[n][3] = 0.f; }

#pragma unroll
    for (int ph = 0; ph < 2; ++ph) {
      __syncthreads();  // previous half (or previous tile) fully consumed
      for (int i = t; i < 4096; i += 512) {
        int row = i >> 4, c8 = (i & 15) << 3;
        bf16x8 v = *(const bf16x8*)(W + row * 256 + ph * 128 + c8);
        *(bf16x8*)swzp(sW, row, row * 256 + (c8 << 1)) = v;
      }
      __syncthreads();

      if (active) {
#pragma unroll
        for (int kc = 0; kc < 4; ++kc) {
          const float* xp = x + (long long)node * 256 + ph * 128 + kc * 32 + h * 8;
          f32x4 fa = *(const f32x4*)xp;
          f32x4 fb = *(const f32x4*)(xp + 4);
          bf16x8 b;
#pragma unroll
          for (int j = 0; j < 4; ++j) { b[j] = (__bf16)fa[j]; b[j + 4] = (__bf16)fb[j]; }
#pragma unroll
          for (int n = 0; n < 16; ++n) {
            int row = n * 16 + l15;
            bf16x8 a = *(const bf16x8*)swzpc(sW, row, row * 256 + kc * 64 + h * 16);
            acc[n] = __builtin_amdgcn_mfma_f32_16x16x32_bf16(a, b, acc[n], 0, 0, 0);
          }
        }
      }
    }

    if (active) {
      if (MODE == 0) {
#pragma unroll
        for (int n = 0; n < 16; ++n) {
          bf16x4 mv;
#pragma unroll
          for (int j = 0; j < 4; ++j) mv[j] = (__bf16)acc[n][j];
          __bf16* dst = (n < 8) ? (hu + (long long)node * 128 + n * 16 + h * 4)
                                : (hw + (long long)node * 128 + (n - 8) * 16 + h * 4);
          *(bf16x4*)dst = mv;
        }
      } else {
        float inv = 1.f / fmaxf((float)cnt[node], 1.0f);
#pragma unroll
        for (int n = 0; n < 8; ++n) {
          f32x4 ag = *(const f32x4*)(sums + (long long)node * 128 + n * 16 + h * 4);
          f32x4 o;
#pragma unroll
          for (int j = 0; j < 4; ++j) {
            float z = acc[n + 8][j] + ag[j] * inv;
            float lr = z >= 0.f ? z : 0.01f * z;
            o[j] = acc[n][j] + lr;
          }
          *(f32x4*)(out + (long long)node * 128 + n * 16 + h * 4) = o;
        }
      }
    }
  }
}

// Fused edge pipeline over TGT-SORTED edges, producer-consumer wave split
// (r12 structure) + consumer-side cross-tile eattr register prefetch:
// consumers read next tile's perm from global and issue eattr loads before
// consuming the current tile, so GEMM1 never waits on HBM.
__global__ __launch_bounds__(1024, 4) void edge_fused(
    const float* __restrict__ eattr, const void* __restrict__ ei,
    const int* __restrict__ flag, const int* __restrict__ perm,
    const __bf16* __restrict__ wE, const __bf16* __restrict__ wA,
    const __bf16* __restrict__ hu, const __bf16* __restrict__ hw,
    float* __restrict__ sums, float* __restrict__ attr_out) {
  __shared__ __bf16 sW1[128 * 128];    // We, swizzled (32 KB)
  __shared__ __bf16 sW2[128 * 128];    // Wattr, swizzled (32 KB)
  __shared__ __bf16 sM[2][128 * 128];  // hs -> msg, dbuf (64 KB)
  __shared__ int sTgt[2][128];         // (1 KB)

  const int t = threadIdx.x;
  const int lane = t & 63;
  const int w = t >> 6;       // 0..15
  const int h = lane >> 4;    // 0..3
  const int l15 = lane & 15;
  const int f = *flag;
  const bool producer = (w >= 8);

  for (int i = t; i < 2048; i += 1024) {
    int row = i >> 4, c8 = (i & 15) << 3;
    bf16x8 v1 = *(const bf16x8*)(wE + row * 128 + c8);
    bf16x8 v2 = *(const bf16x8*)(wA + row * 128 + c8);
    int b = row * 256 + (c8 << 1);
    *(bf16x8*)swzp(sW1, row, b) = v1;
    *(bf16x8*)swzp(sW2, row, b) = v2;
  }

  const int ntiles = NE / 128;  // 12500
  const int tile0 = blockIdx.x;
  if (tile0 >= ntiles) return;
  int buf = 0;

  int pc = 0;            // consumer: current tile's perm'd edge id
  f32x4 fa[4], fb[4];    // consumer: current tile's eattr fragments

  // ---- prologue ----
  if (producer) {
    // producers stage idx + gather hs for tile0 into buf 0
    int q = w - 8;
    int pr = q * 16 + l15;
    int p = perm[(long long)tile0 * 128 + pr];
    int srcI = ld_idx(ei, f, p);
    int tgtI = ld_idx(ei, f, (long long)NE + p);
    sTgt[0][pr] = tgtI;
#pragma unroll
    for (int it = 0; it < 4; ++it) {
      int rr = it * 4 + h;
      int sR = __shfl(srcI, rr);
      int tR = __shfl(tgtI, rr);
      bf16x8 a = *(const bf16x8*)(hu + (long long)sR * 128 + l15 * 8);
      bf16x8 b = *(const bf16x8*)(hw + (long long)tR * 128 + l15 * 8);
      bf16x8 o;
#pragma unroll
      for (int j = 0; j < 8; ++j) o[j] = (__bf16)((float)a[j] + (float)b[j]);
      int R = q * 16 + rr;
      *(bf16x8*)swzp(sM[0], R, R * 256 + l15 * 16) = o;
    }
  } else {
    // consumers prefetch tile0's eattr fragments
    pc = perm[(long long)tile0 * 128 + w * 16 + l15];
    const float* ep = eattr + (long long)pc * 128 + h * 8;
#pragma unroll
    for (int kc = 0; kc < 4; ++kc) {
      fa[kc] = *(const f32x4*)(ep + kc * 32);
      fb[kc] = *(const f32x4*)(ep + kc * 32 + 4);
    }
  }
  __syncthreads();  // weights + sM[0] + idx[0] visible

  for (int tile = tile0; tile < ntiles; tile += gridDim.x) {
    int ntile = tile + gridDim.x;
    bool more = ntile < ntiles;

    if (producer) {
      // ---- produce tile i+1 into sM[buf^1] (wave-local idx via shfl) ----
      if (more) {
        int q = w - 8;
        int pr = q * 16 + l15;
        int p = perm[(long long)ntile * 128 + pr];
        int srcI = ld_idx(ei, f, p);
        int tgtI = ld_idx(ei, f, (long long)NE + p);
        sTgt[buf ^ 1][pr] = tgtI;
#pragma unroll
        for (int it = 0; it < 4; ++it) {
          int rr = it * 4 + h;
          int sR = __shfl(srcI, rr);
          int tR = __shfl(tgtI, rr);
          bf16x8 a = *(const bf16x8*)(hu + (long long)sR * 128 + l15 * 8);
          bf16x8 b = *(const bf16x8*)(hw + (long long)tR * 128 + l15 * 8);
          bf16x8 o;
#pragma unroll
          for (int j = 0; j < 8; ++j) o[j] = (__bf16)((float)a[j] + (float)b[j]);
          int R = q * 16 + rr;
          *(bf16x8*)swzp(sM[buf ^ 1], R, R * 256 + l15 * 16) = o;
        }
      }
    } else {
      // ---- consume tile i from sM[buf] ----
      __bf16* sMb = sM[buf];
      const int myP = pc;
      const int tgtI = sTgt[buf][w * 16 + l15];

      // prefetch NEXT tile's perm + eattr into registers (lands during
      // this tile's compute + stores; consumed at next loop iteration)
      int pn = 0;
      f32x4 fan[4], fbn[4];
      if (more) {
        pn = perm[(long long)ntile * 128 + w * 16 + l15];
        const float* ep2 = eattr + (long long)pn * 128 + h * 8;
#pragma unroll
        for (int kc = 0; kc < 4; ++kc) {
          fan[kc] = *(const f32x4*)(ep2 + kc * 32);
          fbn[kc] = *(const f32x4*)(ep2 + kc * 32 + 4);
        }
      }

      // GEMM1 swapped: acc[n][j] = msg_pre[edge l15][feature n*16 + h*4 + j]
      f32x4 acc[8];
#pragma unroll
      for (int n = 0; n < 8; ++n) { acc[n][0] = 0.f; acc[n][1] = 0.f; acc[n][2] = 0.f; acc[n][3] = 0.f; }
#pragma unroll
      for (int kc = 0; kc < 4; ++kc) {
        bf16x8 bfr;
#pragma unroll
        for (int j = 0; j < 4; ++j) { bfr[j] = (__bf16)fa[kc][j]; bfr[j + 4] = (__bf16)fb[kc][j]; }
#pragma unroll
        for (int n = 0; n < 8; ++n) {
          int row = n * 16 + l15;
          bf16x8 a = *(const bf16x8*)swzpc(sW1, row, row * 256 + kc * 64 + (h << 4));
          acc[n] = __builtin_amdgcn_mfma_f32_16x16x32_bf16(a, bfr, acc[n], 0, 0, 0);
        }
      }

      // vectorized in-place RMW: msg = lrelu(acc + hs); each 8B chunk one lane
      const int R = w * 16 + l15;
#pragma unroll
      for (int n = 0; n < 8; ++n) {
        __bf16* mp = (__bf16*)swzp(sMb, R, R * 256 + n * 32 + h * 8);
        bf16x4 hsv = *(const bf16x4*)mp;
        bf16x4 mv;
#pragma unroll
        for (int j = 0; j < 4; ++j) {
          float z = acc[n][j] + (float)hsv[j];
          float m = z >= 0.f ? z : 0.01f * z;
          mv[j] = (__bf16)m;
        }
        *(bf16x4*)mp = mv;
      }

      // wave-local segment reduce over own 16 sorted edges (coalesced atomics)
      {
        float s0 = 0.f, s1 = 0.f;
        int curT = __shfl(tgtI, 0);
#pragma unroll
        for (int r = 0; r < 16; ++r) {
          int tg = __shfl(tgtI, r);  // wave-uniform
          if (tg != curT) {
            unsafeAtomicAdd(&sums[(long long)curT * 128 + 2 * lane], s0);
            unsafeAtomicAdd(&sums[(long long)curT * 128 + 2 * lane + 1], s1);
            s0 = 0.f; s1 = 0.f; curT = tg;
          }
          int R2 = w * 16 + r;
          bf16x2 v = *(const bf16x2*)swzpc(sMb, R2, R2 * 256 + lane * 4);
          s0 += (float)v[0]; s1 += (float)v[1];
        }
        unsafeAtomicAdd(&sums[(long long)curT * 128 + 2 * lane], s0);
        unsafeAtomicAdd(&sums[(long long)curT * 128 + 2 * lane + 1], s1);
      }

      // GEMM2: attributes = msg @ Wattr^T (A = own-wave msg rows; same-wave
      // ds_write -> ds_read ordering, no barrier needed)
      f32x4 acc2[8];
#pragma unroll
      for (int n = 0; n < 8; ++n) { acc2[n][0] = 0.f; acc2[n][1] = 0.f; acc2[n][2] = 0.f; acc2[n][3] = 0.f; }
#pragma unroll
      for (int ks = 0; ks < 4; ++ks) {
        bf16x8 a2 = *(const bf16x8*)swzpc(sMb, R, R * 256 + ks * 64 + (h << 4));
#pragma unroll
        for (int nt = 0; nt < 8; ++nt) {
          int row = nt * 16 + l15;
          bf16x8 b2 = *(const bf16x8*)swzpc(sW2, row, row * 256 + ks * 64 + (h << 4));
          acc2[nt] = __builtin_amdgcn_mfma_f32_16x16x32_bf16(a2, b2, acc2[nt], 0, 0, 0);
        }
      }

      // store attributes: row = perm'd global edge (via shfl), col = nt*16+l15
      int gp[4];
#pragma unroll
      for (int j = 0; j < 4; ++j) gp[j] = __shfl(myP, (h << 2) + j);
#pragma unroll
      for (int nt = 0; nt < 8; ++nt) {
#pragma unroll
        for (int j = 0; j < 4; ++j) {
          attr_out[(long long)gp[j] * 128 + nt * 16 + l15] = acc2[nt][j];
        }
      }

      // roll the register pipeline
      if (more) {
        pc = pn;
#pragma unroll
        for (int kc = 0; kc < 4; ++kc) { fa[kc] = fan[kc]; fb[kc] = fbn[kc]; }
      }
    }

    __syncthreads();  // tile i consumed + tile i+1 produced
    buf ^= 1;
  }
}

extern "C" void kernel_launch(void* const* d_in, const int* in_sizes, int n_in,
                              void* d_out, int out_size, void* d_ws, size_t ws_size,
                              hipStream_t stream) {
  const float* x     = (const float*)d_in[0];
  const void*  ei    = d_in[1];
  const float* eattr = (const float*)d_in[2];
  const float* We    = (const float*)d_in[3];
  const float* Whu   = (const float*)d_in[4];
  const float* Whw   = (const float*)d_in[5];
  const float* W2    = (const float*)d_in[6];
  const float* Wemb  = (const float*)d_in[7];
  const float* Wattr = (const float*)d_in[8];

  float* out_emb  = (float*)d_out;
  float* out_attr = out_emb + (size_t)NN * 128;

  char* ws = (char*)d_ws;
  float*  sums = (float*)ws;                       // 25,600,000
  int*    cnt  = (int*)(ws + 25600000);            //    200,064
  int*    fill = (int*)(ws + 25800064);            //    200,064
  int*    offs = (int*)(ws + 26000128);            //    200,064
  int*    part = (int*)(ws + 26200192);            //      1,024
  int*    flag = (int*)(ws + 26201216);            //         64
  int*    perm = (int*)(ws + 26201280);            //  6,400,000
  __bf16* hu   = (__bf16*)(ws + 32601280);         // 12,800,000
  __bf16* hw   = (__bf16*)(ws + 45401280);         // 12,800,000
  __bf16* wHUW = (__bf16*)(ws + 58201280);         //    131,072
  __bf16* wET2 = wHUW + 65536;
  __bf16* wE   = wET2 + 65536;
  __bf16* wA   = wE + 16384;

  hipMemsetAsync(ws, 0, 26000128, stream);  // sums + cnt + fill
  detect_idx64<<<1, 1024, 0, stream>>>((const int*)ei, flag);
  prep_weights<<<640, 256, 0, stream>>>(We, Whu, Whw, W2, Wemb, Wattr, wHUW, wET2, wE, wA);
  k_hist<<<6250, 256, 0, stream>>>(ei, flag, cnt);
  k_part<<<196, 256, 0, stream>>>(cnt, part);
  k_scanpart<<<1, 256, 0, stream>>>(part, 196);
  k_offsets<<<196, 256, 0, stream>>>(cnt, part, offs);
  k_scatter<<<6250, 256, 0, stream>>>(ei, flag, offs, fill, perm);
  node_gemm<0><<<391, 512, 0, stream>>>(x, wHUW, hu, hw, nullptr, nullptr, nullptr);
  edge_fused<<<2048, 1024, 0, stream>>>(eattr, ei, flag, perm, wE, wA, hu, hw, sums, out_attr);
  node_gemm<1><<<391, 512, 0, stream>>>(x, wET2, nullptr, nullptr, sums, cnt, out_emb);
}

// Round 14
// 776.433 us; speedup vs baseline: 1.7800x; 1.7800x over previous
//
#include <hip/hip_runtime.h>

#define NN 50000
#define NE 1600000

using bf16x8 = __bf16 __attribute__((ext_vector_type(8)));
using bf16x4 = __bf16 __attribute__((ext_vector_type(4)));
using bf16x2 = __bf16 __attribute__((ext_vector_type(2)));
using f32x4  = float  __attribute__((ext_vector_type(4)));

__device__ __forceinline__ char* swzp(void* base, int row, int byteoff) {
  return (char*)base + (byteoff ^ ((row & 7) << 4));
}
__device__ __forceinline__ const char* swzpc(const void* base, int row, int byteoff) {
  return (const char*)base + (byteoff ^ ((row & 7) << 4));
}

// edge_index may be int32 (JAX default, x64 disabled) or int64. Runtime-detected flag.
__device__ __forceinline__ int ld_idx(const void* p, int f64, long long i) {
  return f64 ? (int)((const long long*)p)[i] : ((const int*)p)[i];
}

__global__ void detect_idx64(const int* ei32, int* flag) {
  __shared__ int anynz;
  if (threadIdx.x == 0) anynz = 0;
  __syncthreads();
  if (ei32[2 * threadIdx.x + 1] != 0) atomicOr(&anynz, 1);
  __syncthreads();
  if (threadIdx.x == 0) *flag = (anynz == 0) ? 1 : 0;
}

__global__ void prep_weights(const float* We, const float* Whu, const float* Whw,
                             const float* W2, const float* Wemb, const float* Wattr,
                             __bf16* wHUW, __bf16* wET2, __bf16* wE, __bf16* wA) {
  int i = blockIdx.x * 256 + threadIdx.x;
  if (i < 65536) {
    int n = i >> 8, k = i & 255;
    wHUW[i] = (__bf16)(n < 128 ? Whu[n * 256 + k] : Whw[(n - 128) * 256 + k]);
  } else if (i < 131072) {
    int j = i - 65536; int n = j >> 8, k = j & 255;
    wET2[j] = (__bf16)(n < 128 ? Wemb[n * 256 + k] : W2[(n - 128) * 256 + k]);
  } else if (i < 147456) {
    int j = i - 131072; wE[j] = (__bf16)We[j];
  } else {
    int j = i - 147456; wA[j] = (__bf16)Wattr[j];
  }
}

// ---- counting sort of edges by tgt ----
__global__ void k_hist(const void* ei, const int* flag, int* cnt) {
  int i = blockIdx.x * 256 + threadIdx.x;
  int t = ld_idx(ei, *flag, (long long)NE + i);
  atomicAdd(&cnt[t], 1);
}

__global__ void k_part(const int* cnt, int* part) {
  __shared__ int red[256];
  int i = blockIdx.x * 256 + threadIdx.x;
  red[threadIdx.x] = (i < NN) ? cnt[i] : 0;
  __syncthreads();
  for (int s = 128; s > 0; s >>= 1) {
    if (threadIdx.x < s) red[threadIdx.x] += red[threadIdx.x + s];
    __syncthreads();
  }
  if (threadIdx.x == 0) part[blockIdx.x] = red[0];
}

__global__ void k_scanpart(int* part, int n) {
  __shared__ int sc[256];
  int v = (threadIdx.x < n) ? part[threadIdx.x] : 0;
  sc[threadIdx.x] = v;
  __syncthreads();
  for (int d = 1; d < 256; d <<= 1) {
    int add = (threadIdx.x >= d) ? sc[threadIdx.x - d] : 0;
    __syncthreads();
    sc[threadIdx.x] += add;
    __syncthreads();
  }
  if (threadIdx.x < n) part[threadIdx.x] = sc[threadIdx.x] - v;  // exclusive
}

__global__ void k_offsets(const int* cnt, const int* part, int* offs) {
  __shared__ int sc[256];
  int i = blockIdx.x * 256 + threadIdx.x;
  int v = (i < NN) ? cnt[i] : 0;
  sc[threadIdx.x] = v;
  __syncthreads();
  for (int d = 1; d < 256; d <<= 1) {
    int add = (threadIdx.x >= d) ? sc[threadIdx.x - d] : 0;
    __syncthreads();
    sc[threadIdx.x] += add;
    __syncthreads();
  }
  if (i < NN) offs[i] = part[blockIdx.x] + sc[threadIdx.x] - v;  // exclusive
}

__global__ void k_scatter(const void* ei, const int* flag, const int* offs,
                          int* fill, int* perm) {
  int i = blockIdx.x * 256 + threadIdx.x;
  int t = ld_idx(ei, *flag, (long long)NE + i);
  int pos = offs[t] + atomicAdd(&fill[t], 1);
  perm[pos] = i;
}

// Swapped-orientation node GEMM (validated round 5): lane owns node l15.
// MODE 0: hu/hw bf16 outputs (W = [W_hu; W_hw]).
// MODE 1: out = emb + lrelu(t2 + sums/max(cnt,1))  (W = [W_emb; W2]).
template <int MODE>
__global__ __launch_bounds__(512) void node_gemm(
    const float* __restrict__ x, const __bf16* __restrict__ W,
    __bf16* __restrict__ hu, __bf16* __restrict__ hw,
    const float* __restrict__ sums, const int* __restrict__ cnt,
    float* __restrict__ out) {
  __shared__ __bf16 sW[256 * 256];  // 128 KB, XOR-swizzled
  const int t = threadIdx.x;
  const int lane = t & 63;
  const int w = t >> 6;      // 0..7
  const int h = lane >> 4;   // 0..3
  const int l15 = lane & 15;

  for (int i = t; i < 8192; i += 512) {
    int row = i >> 5, c8 = (i & 31) << 3;
    bf16x8 v = *(const bf16x8*)(W + row * 256 + c8);
    *(bf16x8*)swzp(sW, row, row * 512 + (c8 << 1)) = v;
  }
  __syncthreads();

  const int ntiles = (NN + 127) / 128;  // 391
  for (int tile = blockIdx.x; tile < ntiles; tile += gridDim.x) {
    int m0 = tile * 128 + w * 16;
    if (m0 >= NN) continue;            // NN % 16 == 0: waves never partial
    int node = m0 + l15;

    f32x4 acc[16];
#pragma unroll
    for (int n = 0; n < 16; ++n) { acc[n][0] = 0.f; acc[n][1] = 0.f; acc[n][2] = 0.f; acc[n][3] = 0.f; }

#pragma unroll
    for (int kc = 0; kc < 8; ++kc) {
      const float* xp = x + (long long)node * 256 + kc * 32 + h * 8;
      f32x4 fa = *(const f32x4*)xp;
      f32x4 fb = *(const f32x4*)(xp + 4);
      bf16x8 b;
#pragma unroll
      for (int j = 0; j < 4; ++j) { b[j] = (__bf16)fa[j]; b[j + 4] = (__bf16)fb[j]; }
#pragma unroll
      for (int n = 0; n < 16; ++n) {
        int row = n * 16 + l15;
        bf16x8 a = *(const bf16x8*)swzpc(sW, row, row * 512 + kc * 64 + h * 16);
        acc[n] = __builtin_amdgcn_mfma_f32_16x16x32_bf16(a, b, acc[n], 0, 0, 0);
      }
    }

    if (MODE == 0) {
#pragma unroll
      for (int n = 0; n < 16; ++n) {
        bf16x4 mv;
#pragma unroll
        for (int j = 0; j < 4; ++j) mv[j] = (__bf16)acc[n][j];
        __bf16* dst = (n < 8) ? (hu + (long long)node * 128 + n * 16 + h * 4)
                              : (hw + (long long)node * 128 + (n - 8) * 16 + h * 4);
        *(bf16x4*)dst = mv;
      }
    } else {
      float inv = 1.f / fmaxf((float)cnt[node], 1.0f);
#pragma unroll
      for (int n = 0; n < 8; ++n) {
        f32x4 ag = *(const f32x4*)(sums + (long long)node * 128 + n * 16 + h * 4);
        f32x4 o;
#pragma unroll
        for (int j = 0; j < 4; ++j) {
          float z = acc[n + 8][j] + ag[j] * inv;
          float lr = z >= 0.f ? z : 0.01f * z;
          o[j] = acc[n][j] + lr;
        }
        *(f32x4*)(out + (long long)node * 128 + n * 16 + h * 4) = o;
      }
    }
  }
}

// Fused edge pipeline over TGT-SORTED edges, producer-consumer wave split
// (r12 verbatim — best measured: edge 556 us, FETCH 989 MB, WRITE 1.03 GB).
// 128-edge tiles, double-buffered sM. Waves 0-7 (consumers) run phase-B
// (GEMM1 -> RMW -> wave-local reduce -> GEMM2 -> store) on sM[buf] while
// waves 8-15 (producers) stage idx + gather hs for tile i+1 into sM[buf^1].
// ONE barrier per tile.
__global__ __launch_bounds__(1024) void edge_fused(
    const float* __restrict__ eattr, const void* __restrict__ ei,
    const int* __restrict__ flag, const int* __restrict__ perm,
    const __bf16* __restrict__ wE, const __bf16* __restrict__ wA,
    const __bf16* __restrict__ hu, const __bf16* __restrict__ hw,
    float* __restrict__ sums, float* __restrict__ attr_out) {
  __shared__ __bf16 sW1[128 * 128];    // We, swizzled (32 KB)
  __shared__ __bf16 sW2[128 * 128];    // Wattr, swizzled (32 KB)
  __shared__ __bf16 sM[2][128 * 128];  // hs -> msg, dbuf (64 KB)
  __shared__ int sPerm[2][128], sTgt[2][128];  // (2 KB)

  const int t = threadIdx.x;
  const int lane = t & 63;
  const int w = t >> 6;       // 0..15
  const int h = lane >> 4;    // 0..3
  const int l15 = lane & 15;
  const int f = *flag;
  const bool producer = (w >= 8);

  for (int i = t; i < 2048; i += 1024) {
    int row = i >> 4, c8 = (i & 15) << 3;
    bf16x8 v1 = *(const bf16x8*)(wE + row * 128 + c8);
    bf16x8 v2 = *(const bf16x8*)(wA + row * 128 + c8);
    int b = row * 256 + (c8 << 1);
    *(bf16x8*)swzp(sW1, row, b) = v1;
    *(bf16x8*)swzp(sW2, row, b) = v2;
  }

  const int ntiles = NE / 128;  // 12500
  const int tile0 = blockIdx.x;
  if (tile0 >= ntiles) return;
  int buf = 0;

  // ---- prologue: producers stage idx + gather hs for tile0 into buf 0 ----
  if (producer) {
    int q = w - 8;              // producer wave 0..7, owns rows q*16..q*16+15
    int pr = q * 16 + l15;
    int p = perm[(long long)tile0 * 128 + pr];
    int srcI = ld_idx(ei, f, p);
    int tgtI = ld_idx(ei, f, (long long)NE + p);
    sPerm[0][pr] = p;
    sTgt[0][pr] = tgtI;
#pragma unroll
    for (int it = 0; it < 4; ++it) {
      int rr = it * 4 + h;      // row within wave's 16
      int sR = __shfl(srcI, rr);
      int tR = __shfl(tgtI, rr);
      bf16x8 a = *(const bf16x8*)(hu + (long long)sR * 128 + l15 * 8);
      bf16x8 b = *(const bf16x8*)(hw + (long long)tR * 128 + l15 * 8);
      bf16x8 o;
#pragma unroll
      for (int j = 0; j < 8; ++j) o[j] = (__bf16)((float)a[j] + (float)b[j]);
      int R = q * 16 + rr;
      *(bf16x8*)swzp(sM[0], R, R * 256 + l15 * 16) = o;
    }
  }
  __syncthreads();  // weights + sM[0] + idx[0] visible

  for (int tile = tile0; tile < ntiles; tile += gridDim.x) {
    int ntile = tile + gridDim.x;
    bool more = ntile < ntiles;

    if (producer) {
      // ---- produce tile i+1 into sM[buf^1] (wave-local idx via shfl) ----
      if (more) {
        int q = w - 8;
        int pr = q * 16 + l15;
        int p = perm[(long long)ntile * 128 + pr];
        int srcI = ld_idx(ei, f, p);
        int tgtI = ld_idx(ei, f, (long long)NE + p);
        sPerm[buf ^ 1][pr] = p;
        sTgt[buf ^ 1][pr] = tgtI;
#pragma unroll
        for (int it = 0; it < 4; ++it) {
          int rr = it * 4 + h;
          int sR = __shfl(srcI, rr);
          int tR = __shfl(tgtI, rr);
          bf16x8 a = *(const bf16x8*)(hu + (long long)sR * 128 + l15 * 8);
          bf16x8 b = *(const bf16x8*)(hw + (long long)tR * 128 + l15 * 8);
          bf16x8 o;
#pragma unroll
          for (int j = 0; j < 8; ++j) o[j] = (__bf16)((float)a[j] + (float)b[j]);
          int R = q * 16 + rr;
          *(bf16x8*)swzp(sM[buf ^ 1], R, R * 256 + l15 * 16) = o;
        }
      }
    } else {
      // ---- consume tile i from sM[buf] ----
      __bf16* sMb = sM[buf];
      const int myP = sPerm[buf][w * 16 + l15];
      const int tgtI = sTgt[buf][w * 16 + l15];
      const float* ep = eattr + (long long)myP * 128 + h * 8;
      f32x4 fa[4], fb[4];
#pragma unroll
      for (int kc = 0; kc < 4; ++kc) {
        fa[kc] = *(const f32x4*)(ep + kc * 32);
        fb[kc] = *(const f32x4*)(ep + kc * 32 + 4);
      }

      // GEMM1 swapped: acc[n][j] = msg_pre[edge l15][feature n*16 + h*4 + j]
      f32x4 acc[8];
#pragma unroll
      for (int n = 0; n < 8; ++n) { acc[n][0] = 0.f; acc[n][1] = 0.f; acc[n][2] = 0.f; acc[n][3] = 0.f; }
#pragma unroll
      for (int kc = 0; kc < 4; ++kc) {
        bf16x8 bfr;
#pragma unroll
        for (int j = 0; j < 4; ++j) { bfr[j] = (__bf16)fa[kc][j]; bfr[j + 4] = (__bf16)fb[kc][j]; }
#pragma unroll
        for (int n = 0; n < 8; ++n) {
          int row = n * 16 + l15;
          bf16x8 a = *(const bf16x8*)swzpc(sW1, row, row * 256 + kc * 64 + (h << 4));
          acc[n] = __builtin_amdgcn_mfma_f32_16x16x32_bf16(a, bfr, acc[n], 0, 0, 0);
        }
      }

      // vectorized in-place RMW: msg = lrelu(acc + hs); each 8B chunk one lane
      const int R = w * 16 + l15;
#pragma unroll
      for (int n = 0; n < 8; ++n) {
        __bf16* mp = (__bf16*)swzp(sMb, R, R * 256 + n * 32 + h * 8);
        bf16x4 hsv = *(const bf16x4*)mp;
        bf16x4 mv;
#pragma unroll
        for (int j = 0; j < 4; ++j) {
          float z = acc[n][j] + (float)hsv[j];
          float m = z >= 0.f ? z : 0.01f * z;
          mv[j] = (__bf16)m;
        }
        *(bf16x4*)mp = mv;
      }

      // wave-local segment reduce over own 16 sorted edges (coalesced atomics)
      {
        float s0 = 0.f, s1 = 0.f;
        int curT = __shfl(tgtI, 0);
#pragma unroll
        for (int r = 0; r < 16; ++r) {
          int tg = __shfl(tgtI, r);  // wave-uniform
          if (tg != curT) {
            unsafeAtomicAdd(&sums[(long long)curT * 128 + 2 * lane], s0);
            unsafeAtomicAdd(&sums[(long long)curT * 128 + 2 * lane + 1], s1);
            s0 = 0.f; s1 = 0.f; curT = tg;
          }
          int R2 = w * 16 + r;
          bf16x2 v = *(const bf16x2*)swzpc(sMb, R2, R2 * 256 + lane * 4);
          s0 += (float)v[0]; s1 += (float)v[1];
        }
        unsafeAtomicAdd(&sums[(long long)curT * 128 + 2 * lane], s0);
        unsafeAtomicAdd(&sums[(long long)curT * 128 + 2 * lane + 1], s1);
      }

      // GEMM2: attributes = msg @ Wattr^T (A = own-wave msg rows; same-wave
      // ds_write -> ds_read ordering, no barrier needed)
      f32x4 acc2[8];
#pragma unroll
      for (int n = 0; n < 8; ++n) { acc2[n][0] = 0.f; acc2[n][1] = 0.f; acc2[n][2] = 0.f; acc2[n][3] = 0.f; }
#pragma unroll
      for (int ks = 0; ks < 4; ++ks) {
        bf16x8 a2 = *(const bf16x8*)swzpc(sMb, R, R * 256 + ks * 64 + (h << 4));
#pragma unroll
        for (int nt = 0; nt < 8; ++nt) {
          int row = nt * 16 + l15;
          bf16x8 b2 = *(const bf16x8*)swzpc(sW2, row, row * 256 + ks * 64 + (h << 4));
          acc2[nt] = __builtin_amdgcn_mfma_f32_16x16x32_bf16(a2, b2, acc2[nt], 0, 0, 0);
        }
      }

      // store attributes: row = perm'd global edge (via shfl), col = nt*16+l15
      int gp[4];
#pragma unroll
      for (int j = 0; j < 4; ++j) gp[j] = __shfl(myP, (h << 2) + j);
#pragma unroll
      for (int nt = 0; nt < 8; ++nt) {
#pragma unroll
        for (int j = 0; j < 4; ++j) {
          attr_out[(long long)gp[j] * 128 + nt * 16 + l15] = acc2[nt][j];
        }
      }
    }

    __syncthreads();  // tile i consumed + tile i+1 produced
    buf ^= 1;
  }
}

extern "C" void kernel_launch(void* const* d_in, const int* in_sizes, int n_in,
                              void* d_out, int out_size, void* d_ws, size_t ws_size,
                              hipStream_t stream) {
  const float* x     = (const float*)d_in[0];
  const void*  ei    = d_in[1];
  const float* eattr = (const float*)d_in[2];
  const float* We    = (const float*)d_in[3];
  const float* Whu   = (const float*)d_in[4];
  const float* Whw   = (const float*)d_in[5];
  const float* W2    = (const float*)d_in[6];
  const float* Wemb  = (const float*)d_in[7];
  const float* Wattr = (const float*)d_in[8];

  float* out_emb  = (float*)d_out;
  float* out_attr = out_emb + (size_t)NN * 128;

  char* ws = (char*)d_ws;
  float*  sums = (float*)ws;                       // 25,600,000
  int*    cnt  = (int*)(ws + 25600000);            //    200,064
  int*    fill = (int*)(ws + 25800064);            //    200,064
  int*    offs = (int*)(ws + 26000128);            //    200,064
  int*    part = (int*)(ws + 26200192);            //      1,024
  int*    flag = (int*)(ws + 26201216);            //         64
  int*    perm = (int*)(ws + 26201280);            //  6,400,000
  __bf16* hu   = (__bf16*)(ws + 32601280);         // 12,800,000
  __bf16* hw   = (__bf16*)(ws + 45401280);         // 12,800,000
  __bf16* wHUW = (__bf16*)(ws + 58201280);         //    131,072
  __bf16* wET2 = wHUW + 65536;
  __bf16* wE   = wET2 + 65536;
  __bf16* wA   = wE + 16384;

  hipMemsetAsync(ws, 0, 26000128, stream);  // sums + cnt + fill
  detect_idx64<<<1, 1024, 0, stream>>>((const int*)ei, flag);
  prep_weights<<<640, 256, 0, stream>>>(We, Whu, Whw, W2, Wemb, Wattr, wHUW, wET2, wE, wA);
  k_hist<<<6250, 256, 0, stream>>>(ei, flag, cnt);
  k_part<<<196, 256, 0, stream>>>(cnt, part);
  k_scanpart<<<1, 256, 0, stream>>>(part, 196);
  k_offsets<<<196, 256, 0, stream>>>(cnt, part, offs);
  k_scatter<<<6250, 256, 0, stream>>>(ei, flag, offs, fill, perm);
  node_gemm<0><<<256, 512, 0, stream>>>(x, wHUW, hu, hw, nullptr, nullptr, nullptr);
  edge_fused<<<2048, 1024, 0, stream>>>(eattr, ei, flag, perm, wE, wA, hu, hw, sums, out_attr);
  node_gemm<1><<<256, 512, 0, stream>>>(x, wET2, nullptr, nullptr, sums, cnt, out_emb);
}